// Round 8
// baseline (478.958 us; speedup 1.0000x reference)
//
#include <hip/hip_runtime.h>
#include <math.h>

#define DD 64
#define BIGF 1.0e9f

// uniform-lane broadcast via v_readlane (no DS pipe)
__device__ __forceinline__ float bcastf(float x, int lane) {
    return __builtin_bit_cast(float, __builtin_amdgcn_readlane(__builtin_bit_cast(int, x), lane));
}
__device__ __forceinline__ int bcasti(int x, int lane) {
    return __builtin_amdgcn_readlane(x, lane);
}

// full-wave64 min via DPP (pure VALU): row_shr 1/2/4/8 + row_bcast15/31.
__device__ __forceinline__ float wave_min64(float x) {
#define STEPD(ctrl)                                                                \
    {                                                                              \
        int _t = __builtin_amdgcn_update_dpp(__builtin_bit_cast(int, x),           \
                                             __builtin_bit_cast(int, x),           \
                                             ctrl, 0xF, 0xF, false);               \
        x = fminf(x, __builtin_bit_cast(float, _t));                               \
    }
    STEPD(0x111)  // row_shr:1
    STEPD(0x112)  // row_shr:2
    STEPD(0x114)  // row_shr:4
    STEPD(0x118)  // row_shr:8
    STEPD(0x142)  // row_bcast:15
    STEPD(0x143)  // row_bcast:31
#undef STEPD
    return bcastf(x, 63);
}

// ---- Fused: per-wave cost staging (bit-exact r1..r7 ops) + JV solve. ----
// 256-thread blocks = 4 independent waves, 1 sample each.
// Prologue: lane l computes cost[i][l] = -(gamma[i][l] + -log(-log(clip(u[i][l]))))
// for all i (logs in double, rounded to f32), stores to this sample's region
// of the output buffer (used as scratch), waits vmcnt, then solves from L2.
// Solve: lane l owns column j=l+1 state (v,minv,way,p,used) and row r=l+1
// dual u. Bit-exact f32 replication of the reference JV trajectory (see r6
// notes: minv doubles as the masked array; minv -= (delta-du) is exact;
// u[i0] prefetch reads lane pj1-1 before its ud update - not yet inTree).
// Each wave overwrites its cost region with the one-hot output at the end.
__global__ __launch_bounds__(256, 8) void lap64_fused(
    const float* __restrict__ gamma,
    const float* __restrict__ uin,
    float* __restrict__ cost,
    int nsamp)
{
    const int l = threadIdx.x & 63;
    const int b = blockIdx.x * 4 + (threadIdx.x >> 6);
    if (b >= nsamp) return;
    float* cb = cost + (size_t)b * (DD * DD);
    const float* ub = uin + (size_t)b * (DD * DD);

    // ---- prologue: stage this sample's cost matrix ----
    const float lo = 1e-20f;
    const float hi = (float)(1.0 - 1e-7);
    #pragma unroll 4
    for (int i = 0; i < DD; ++i) {
        float uu = ub[i * DD + l];
        float x  = fminf(fmaxf(uu, lo), hi);
        float inner = (float)log((double)x);
        float outer = (float)log((double)(-inner));
        float sc = gamma[i * DD + l] + (-outer);
        cb[i * DD + l] = -sc;
    }
    // make this wave's stores visible to its own loads below
    asm volatile("s_waitcnt vmcnt(0)" ::: "memory");

    // ---- solve ----
    float v  = 0.0f;  // v[l+1]
    float ud = 0.0f;  // u[l+1]
    int   p  = 0;     // p[l+1] (1-based row matched to column l+1; 0 = none)

    for (int i = 0; i < DD; ++i) {
        float minv = BIGF;
        int   way  = 0;
        bool  used = false;
        bool  inTree = (l == i);      // row i+1 enters tree via virtual col 0
        int   j0 = 0;
        float c    = cb[i * DD + l];  // row i0-1 = i
        float u_i0 = bcastf(ud, i);   // u[i+1]

        for (int it = 0; it <= DD; ++it) {
            float cur = (c - u_i0) - v;            // ((cost - u) - v), as reference
            bool bett = (!used) && (cur < minv);
            minv = bett ? cur : minv;              // used lanes stay at BIG
            way  = bett ? j0  : way;

            float delta = wave_min64(minv);        // minv is already masked
            unsigned long long tie = __ballot(minv == delta);
            int j1 = __ffsll(tie);                 // first-index tie-break
            j1 = __builtin_amdgcn_readfirstlane(j1);
            int pj1 = bcasti(p, j1 - 1);

            // prefetch next row + next u[i0] (lane pj1-1 not yet inTree)
            if (pj1 != 0) {
                c    = cb[(pj1 - 1) * DD + l];
                u_i0 = bcastf(ud, pj1 - 1);
            }

            // dual updates (reference's where()-updates, exact)
            float du = used ? delta : 0.0f;
            float di = inTree ? delta : 0.0f;
            ud += di;
            v  -= du;
            minv -= (delta - du);                  // used: -0 (BIG kept); unused: -delta

            bool isj1 = (l == (j1 - 1));
            used = used || isj1;
            minv = isj1 ? BIGF : minv;             // inject BIG for newly-used lane
            j0 = j1;
            if (pj1 == 0) break;
            inTree = inTree || (l == (pj1 - 1));
        }

        // ---- augment along way[] chain ----
        while (j0 != 0) {
            int jn = bcasti(way, j0 - 1);
            int pn = (jn == 0) ? (i + 1) : bcasti(p, jn - 1);
            if (l == (j0 - 1)) p = pn;
            j0 = jn;
        }
    }

    // ---- overwrite cost region with one-hot permutation: out[b][p-1][l] = 1 ----
    const int prow = p - 1;
    #pragma nounroll
    for (int r = 0; r < DD; ++r) {
        cb[r * DD + l] = (prow == r) ? 1.0f : 0.0f;
    }
}

extern "C" void kernel_launch(void* const* d_in, const int* in_sizes, int n_in,
                              void* d_out, int out_size, void* d_ws, size_t ws_size,
                              hipStream_t stream) {
    const float* gamma = (const float*)d_in[0];
    const float* u     = (const float*)d_in[1];
    float* out = (float*)d_out;
    const int nsamp = in_sizes[1] / (DD * DD);

    lap64_fused<<<dim3((nsamp + 3) / 4), dim3(256), 0, stream>>>(gamma, u, out, nsamp);
}

// Round 9
// 360.923 us; speedup vs baseline: 1.3270x; 1.3270x over previous
//
#include <hip/hip_runtime.h>
#include <math.h>

#define DD 64
#define BIGF 1.0e9f

// uniform-lane broadcast via v_readlane (no DS pipe)
__device__ __forceinline__ float bcastf(float x, int lane) {
    return __builtin_bit_cast(float, __builtin_amdgcn_readlane(__builtin_bit_cast(int, x), lane));
}
__device__ __forceinline__ int bcasti(int x, int lane) {
    return __builtin_amdgcn_readlane(x, lane);
}

// full-wave64 min via DPP (pure VALU): row_shr 1/2/4/8 + row_bcast15/31.
__device__ __forceinline__ float wave_min64(float x) {
#define STEPD(ctrl)                                                                \
    {                                                                              \
        int _t = __builtin_amdgcn_update_dpp(__builtin_bit_cast(int, x),           \
                                             __builtin_bit_cast(int, x),           \
                                             ctrl, 0xF, 0xF, false);               \
        x = fminf(x, __builtin_bit_cast(float, _t));                               \
    }
    STEPD(0x111)  // row_shr:1
    STEPD(0x112)  // row_shr:2
    STEPD(0x114)  // row_shr:4
    STEPD(0x118)  // row_shr:8
    STEPD(0x142)  // row_bcast:15
    STEPD(0x143)  // row_bcast:31
#undef STEPD
    return bcastf(x, 63);
}

// ---- fast f64 log, f32-correctly-rounded for all practical inputs ----
// x = 2^e * m, m in [1,2); idx = top-7 mantissa bits; c = 1+(2*idx+1)/256.
// log(x) = e*ln2 + log(1/inv_c) + log1p(m*inv_c - 1), |r| <= 2^-8.
// Degree-6 log1p poly: truncation ~2^-56; total rel err ~2^-50 -> expected
// wrong-f32-rounding count over 67M calls ~ 1 (vs libm-exact reference).
__device__ __forceinline__ double fast_log(double d, const double2* __restrict__ tbl) {
    long long bits = __double_as_longlong(d);
    int e = (int)(bits >> 52) - 1023;
    double m = __longlong_as_double((bits & 0x000FFFFFFFFFFFFFLL) | 0x3FF0000000000000LL);
    int idx = (int)(bits >> 45) & 127;
    double2 t = tbl[idx];                 // t.x = inv_c (rounded), t.y = -log(inv_c)
    double r  = fma(m, t.x, -1.0);
    double r2 = r * r;
    double q = fma(r, -1.0 / 6.0, 0.2);
    q = fma(q, r, -0.25);
    q = fma(q, r, 1.0 / 3.0);
    q = fma(q, r, -0.5);
    double res = fma(q, r2, r);           // log1p(r)
    return fma((double)e, 0.69314718055994530942, t.y + res);
}

// ---- Stage: cost = -(gamma + gumbel), gumbel = -log(-log(clip(u))) ----
// Grid-strided; per-block 128-entry log table in LDS.
__global__ __launch_bounds__(256) void stage_kernel(
    const float* __restrict__ gamma,
    const float* __restrict__ uin,
    float* __restrict__ cost,
    int total4)
{
    __shared__ double2 tbl[128];
    {
        int t = threadIdx.x;
        if (t < 128) {
            double c = 1.0 + (double)(2 * t + 1) * (1.0 / 256.0);  // exact
            double inv = 1.0 / c;                                  // rounded
            tbl[t].x = inv;
            tbl[t].y = -log(inv);                                  // = log(1/inv), libm once
        }
    }
    __syncthreads();

    const float lo = 1e-20f;
    const float hi = (float)(1.0 - 1e-7);
    const int stride = gridDim.x * blockDim.x;

    for (int idx = blockIdx.x * blockDim.x + threadIdx.x; idx < total4; idx += stride) {
        float4 u4 = ((const float4*)uin)[idx];
        int e = idx << 2;
        const float4 g4 = *(const float4*)(gamma + (e & (DD * DD - 1)));

        float uu[4] = {u4.x, u4.y, u4.z, u4.w};
        float gg[4] = {g4.x, g4.y, g4.z, g4.w};
        float rr[4];
#pragma unroll
        for (int k = 0; k < 4; ++k) {
            float x = fminf(fmaxf(uu[k], lo), hi);
            float inner = (float)fast_log((double)x, tbl);
            float outer = (float)fast_log((double)(-inner), tbl);
            float sc = gg[k] + (-outer);
            rr[k] = -sc;
        }
        float4 r4 = {rr[0], rr[1], rr[2], rr[3]};
        ((float4*)cost)[idx] = r4;
    }
}

// ---- LAP: 256-thread blocks = 4 independent waves, 1 sample each. ----
// Lane l owns column j=l+1 state (v,minv,way,p,used) and row r=l+1 dual u.
// Bit-exact f32 replication of the reference JV trajectory (r6 notes:
// minv doubles as the masked array; minv -= (delta-du) is exact; u[i0]
// prefetch reads lane pj1-1 before its ud update - not yet inTree).
// Each wave overwrites its sample's cost region with the one-hot output.
__global__ __launch_bounds__(256, 8) void lap64_kernel(float* __restrict__ cost, int nsamp)
{
    const int l = threadIdx.x & 63;
    const int b = blockIdx.x * 4 + (threadIdx.x >> 6);
    if (b >= nsamp) return;
    float* cb = cost + (size_t)b * (DD * DD);

    float v  = 0.0f;  // v[l+1]
    float ud = 0.0f;  // u[l+1]
    int   p  = 0;     // p[l+1] (1-based row matched to column l+1; 0 = none)

    for (int i = 0; i < DD; ++i) {
        float minv = BIGF;
        int   way  = 0;
        bool  used = false;
        bool  inTree = (l == i);      // row i+1 enters tree via virtual col 0
        int   j0 = 0;
        float c    = cb[i * DD + l];  // row i0-1 = i
        float u_i0 = bcastf(ud, i);   // u[i+1]

        for (int it = 0; it <= DD; ++it) {
            float cur = (c - u_i0) - v;            // ((cost - u) - v), as reference
            bool bett = (!used) && (cur < minv);
            minv = bett ? cur : minv;              // used lanes stay at BIG
            way  = bett ? j0  : way;

            float delta = wave_min64(minv);        // minv is already masked
            unsigned long long tie = __ballot(minv == delta);
            int j1 = __ffsll(tie);                 // first-index tie-break
            j1 = __builtin_amdgcn_readfirstlane(j1);
            int pj1 = bcasti(p, j1 - 1);

            // prefetch next row + next u[i0] (lane pj1-1 not yet inTree)
            if (pj1 != 0) {
                c    = cb[(pj1 - 1) * DD + l];
                u_i0 = bcastf(ud, pj1 - 1);
            }

            // dual updates (reference's where()-updates, exact)
            float du = used ? delta : 0.0f;
            float di = inTree ? delta : 0.0f;
            ud += di;
            v  -= du;
            minv -= (delta - du);                  // used: -0 (BIG kept); unused: -delta

            bool isj1 = (l == (j1 - 1));
            used = used || isj1;
            minv = isj1 ? BIGF : minv;             // inject BIG for newly-used lane
            j0 = j1;
            if (pj1 == 0) break;
            inTree = inTree || (l == (pj1 - 1));
        }

        // ---- augment along way[] chain ----
        while (j0 != 0) {
            int jn = bcasti(way, j0 - 1);
            int pn = (jn == 0) ? (i + 1) : bcasti(p, jn - 1);
            if (l == (j0 - 1)) p = pn;
            j0 = jn;
        }
    }

    // ---- overwrite cost region with one-hot permutation: out[b][p-1][l] = 1 ----
    const int prow = p - 1;
    #pragma nounroll
    for (int r = 0; r < DD; ++r) {
        cb[r * DD + l] = (prow == r) ? 1.0f : 0.0f;
    }
}

extern "C" void kernel_launch(void* const* d_in, const int* in_sizes, int n_in,
                              void* d_out, int out_size, void* d_ws, size_t ws_size,
                              hipStream_t stream) {
    const float* gamma = (const float*)d_in[0];
    const float* u     = (const float*)d_in[1];
    float* out = (float*)d_out;
    const int nsamp = in_sizes[1] / (DD * DD);
    const int total4 = nsamp * DD * DD / 4;

    stage_kernel<<<dim3(4096), dim3(256), 0, stream>>>(gamma, u, out, total4);
    lap64_kernel<<<dim3((nsamp + 3) / 4), dim3(256), 0, stream>>>(out, nsamp);
}